// Round 2
// baseline (998.915 us; speedup 1.0000x reference)
//
#include <hip/hip_runtime.h>
#include <math.h>

#define NEURONS 54
#define DT 4
#define STEPS 30
#define BATCH 16
#define HW 75
#define P 5625        // 75*75
#define PPAD 5632     // padded to multiple of 4 (16B float4 alignment); 5632 = 22*256
#define PPAD4 (PPAD/4)
#define NFRAMES (BATCH*STEPS)   // 480
#define FPB 4                   // frames per fc block

// ---------------------------------------------------------------------------
// Kernel W: repack fc_w [54][5625] -> [54][5632], zero-padded rows so each row
// is 16B-aligned for dwordx4 loads in the FC kernel.
// ---------------------------------------------------------------------------
__global__ void repack_w(const float* __restrict__ fc_w, float* __restrict__ wpad) {
    int idx = blockIdx.x * blockDim.x + threadIdx.x;
    if (idx >= NEURONS * PPAD) return;
    int n = idx / PPAD, p = idx % PPAD;
    wpad[idx] = (p < P) ? fc_w[n * P + p] : 0.0f;
}

// ---------------------------------------------------------------------------
// Kernel P: pure-streaming 8x8 avg-pool. One thread per (padded) pooled
// output. grid = (5632/256, 480); no LDS, no syncs — max latency hiding.
// Consecutive lanes read 32B-strided bases -> full cache-line utilization
// across the two dwordx4 loads per row.
// ---------------------------------------------------------------------------
__global__ __launch_bounds__(256) void pool_k(
    const float* __restrict__ x, float* __restrict__ xp) {
    const int p  = blockIdx.x * 256 + threadIdx.x;   // 0..5631
    const int bt = blockIdx.y;                        // 0..479
    if (p >= P) {
        xp[(size_t)bt * PPAD + p] = 0.0f;             // zero pad tail
        return;
    }
    const int ph = p / HW, pw = p - ph * HW;
    const float* base = x + (size_t)bt * (600 * 600) + (ph * 8) * 600 + pw * 8;
    float acc = 0.0f;
    #pragma unroll
    for (int r = 0; r < 8; r++) {
        const float4* row = (const float4*)(base + r * 600);
        float4 a = row[0], b4 = row[1];
        acc += (a.x + b4.x) + (a.y + b4.y) + (a.z + b4.z) + (a.w + b4.w);
    }
    xp[(size_t)bt * PPAD + p] = acc * (1.0f / 64.0f);
}

// ---------------------------------------------------------------------------
// Kernel F: FC over pooled frames. FPB=4 frames per block -> 120 blocks (one
// round over 256 CUs), frames staged in LDS, each w float4 load amortized
// over 4 frames (w L2 traffic /4).
// Same chunked summation order as the exact-match R1 kernel.
// ---------------------------------------------------------------------------
__global__ __launch_bounds__(512) void fc_k(
    const float* __restrict__ xp, const float* __restrict__ wpad,
    const float* __restrict__ fc_b, float* __restrict__ frames) {
    __shared__ __align__(16) float xs[FPB][PPAD];
    __shared__ float partial[FPB][NEURONS * 8];
    const int tid = threadIdx.x;
    const int f0 = blockIdx.x * FPB;

    // stage 4 frames: 5632 float4s via 512 threads (11 each)
    const float4* src = (const float4*)(xp + (size_t)f0 * PPAD);
    float4* dst = (float4*)(&xs[0][0]);
    #pragma unroll
    for (int i = tid; i < FPB * PPAD4; i += 512) dst[i] = src[i];
    __syncthreads();

    if (tid < NEURONS * 8) {
        const int n = tid >> 3, c = tid & 7;
        const float4* w4 = (const float4*)(wpad + n * PPAD);
        float acc[FPB] = {0.f, 0.f, 0.f, 0.f};
        for (int i = c; i < PPAD4; i += 8) {
            float4 w = w4[i];
            #pragma unroll
            for (int f = 0; f < FPB; f++) {
                float4 a = ((const float4*)xs[f])[i];   // broadcast across n -> no bank conflict
                acc[f] += a.x * w.x + a.y * w.y + a.z * w.z + a.w * w.w;
            }
        }
        #pragma unroll
        for (int f = 0; f < FPB; f++) partial[f][tid] = acc[f];
    }
    __syncthreads();

    if (tid < FPB * NEURONS) {
        const int f = tid / NEURONS, n = tid - f * NEURONS;
        float s = 0.0f;
        #pragma unroll
        for (int c = 0; c < 8; c++) s += partial[f][n * 8 + c];
        frames[(size_t)(f0 + f) * NEURONS + n] = s + fc_b[n];
    }
}

// ---------------------------------------------------------------------------
// Kernel S: 30-step recurrent scan. One block, 1024 threads.
// wave = batch b (16 waves), lane = neuron n (lanes 54..63 idle with 0s).
// ---------------------------------------------------------------------------
__global__ __launch_bounds__(1024) void scan_k(
    const float* __restrict__ frames, const float* __restrict__ l_weight,
    const float* __restrict__ h_weight, float* __restrict__ out) {
    const int tid = threadIdx.x;
    const int b = tid >> 6;     // wave id = batch
    const int n = tid & 63;     // lane = neuron
    const bool active = (n < NEURONS);

    float lw[DT], hw_[DT];
    #pragma unroll
    for (int d = 0; d < DT; d++) {
        lw[d]  = active ? l_weight[n * DT + d] : 0.0f;
        hw_[d] = h_weight[d];
    }
    float hist[DT] = {0.f, 0.f, 0.f, 0.f};
    float count = 0.f;
    __shared__ float wls[16];

    for (int t = 0; t < STEPS; t++) {
        float my_hsum = 0.f, hterm = 0.f;
        #pragma unroll
        for (int d = 0; d < DT; d++) {
            my_hsum += hist[d] * lw[d];
            hterm   += hist[d] * hw_[d];
        }
        float tot = my_hsum;
        #pragma unroll
        for (int off = 32; off > 0; off >>= 1) tot += __shfl_xor(tot, off, 64);

        float rate = 0.f;
        if (active) {
            float cur = frames[(b * STEPS + t) * NEURONS + n] + (tot - my_hsum) + hterm;
            rate = expf(cur);
        }
        float rsum = rate;
        #pragma unroll
        for (int off = 32; off > 0; off >>= 1) rsum += __shfl_xor(rsum, off, 64);
        __syncthreads();
        if (n == 0) wls[b] = rsum;
        __syncthreads();
        float v = (n < 16) ? wls[n] : 0.f;
        #pragma unroll
        for (int off = 32; off > 0; off >>= 1) v += __shfl_xor(v, off, 64);
        float thr = v * (1.0f / (BATCH * NEURONS));

        float s = (active && rate > thr) ? 1.0f : 0.0f;
        count += s;
        hist[0] = hist[1]; hist[1] = hist[2]; hist[2] = hist[3]; hist[3] = s;
    }
    if (active) {
        out[b * NEURONS + n] = count + log1pf(expf(-count));
    }
}

extern "C" void kernel_launch(void* const* d_in, const int* in_sizes, int n_in,
                              void* d_out, int out_size, void* d_ws, size_t ws_size,
                              hipStream_t stream) {
    const float* x        = (const float*)d_in[0];
    const float* fc_w     = (const float*)d_in[1];
    const float* fc_b     = (const float*)d_in[2];
    const float* l_weight = (const float*)d_in[3];
    const float* h_weight = (const float*)d_in[4];
    float* out = (float*)d_out;

    float* wpad   = (float*)d_ws;                       // 54*5632 floats
    float* xp     = wpad + NEURONS * PPAD;              // 480*5632 floats (10.8 MB)
    float* frames = xp + (size_t)NFRAMES * PPAD;        // 480*54 floats

    int wtotal = NEURONS * PPAD;
    repack_w<<<(wtotal + 511) / 512, 512, 0, stream>>>(fc_w, wpad);
    pool_k<<<dim3(PPAD / 256, NFRAMES), 256, 0, stream>>>(x, xp);
    fc_k<<<NFRAMES / FPB, 512, 0, stream>>>(xp, wpad, fc_b, frames);
    scan_k<<<1, 1024, 0, stream>>>(frames, l_weight, h_weight, out);
}

// Round 3
// 993.706 us; speedup vs baseline: 1.0052x; 1.0052x over previous
//
#include <hip/hip_runtime.h>
#include <math.h>

#define NEURONS 54
#define DT 4
#define STEPS 30
#define BATCH 16
#define HW 75
#define P 5625        // 75*75
#define PPAD 5632     // padded to multiple of 4 (16B float4 alignment); 5632 = 22*256
#define PPAD4 (PPAD/4)
#define NFRAMES (BATCH*STEPS)   // 480
#define FPB 2                   // frames per fc block -> 240 blocks, 48.5 KB LDS

// ---------------------------------------------------------------------------
// Kernel W: repack fc_w [54][5625] -> [54][5632], zero-padded rows so each row
// is 16B-aligned for dwordx4 loads in the FC kernel.
// ---------------------------------------------------------------------------
__global__ void repack_w(const float* __restrict__ fc_w, float* __restrict__ wpad) {
    int idx = blockIdx.x * blockDim.x + threadIdx.x;
    if (idx >= NEURONS * PPAD) return;
    int n = idx / PPAD, p = idx % PPAD;
    wpad[idx] = (p < P) ? fc_w[n * P + p] : 0.0f;
}

// ---------------------------------------------------------------------------
// Kernel P: pure-streaming 8x8 avg-pool. One thread per (padded) pooled
// output. grid = (22, 480); no LDS, no syncs — max latency hiding. This is
// the single pass over x (691 MB) that sets the floor (~110 us @ 6.3 TB/s).
// ---------------------------------------------------------------------------
__global__ __launch_bounds__(256) void pool_k(
    const float* __restrict__ x, float* __restrict__ xp) {
    const int p  = blockIdx.x * 256 + threadIdx.x;   // 0..5631
    const int bt = blockIdx.y;                        // 0..479
    if (p >= P) {
        xp[(size_t)bt * PPAD + p] = 0.0f;             // zero pad tail
        return;
    }
    const int ph = p / HW, pw = p - ph * HW;
    const float* base = x + (size_t)bt * (600 * 600) + (ph * 8) * 600 + pw * 8;
    float acc = 0.0f;
    #pragma unroll
    for (int r = 0; r < 8; r++) {
        const float4* row = (const float4*)(base + r * 600);
        float4 a = row[0], b4 = row[1];
        acc += (a.x + b4.x) + (a.y + b4.y) + (a.z + b4.z) + (a.w + b4.w);
    }
    xp[(size_t)bt * PPAD + p] = acc * (1.0f / 64.0f);
}

// ---------------------------------------------------------------------------
// Kernel F: FC over pooled frames. FPB=2 frames per block -> 240 blocks
// (94% CU coverage), 48.5 KB LDS. Per-frame summation order is bit-identical
// to the passing R1/R2 kernels (same n/c chunk assignment, same i stride).
// ---------------------------------------------------------------------------
__global__ __launch_bounds__(512) void fc_k(
    const float* __restrict__ xp, const float* __restrict__ wpad,
    const float* __restrict__ fc_b, float* __restrict__ frames) {
    __shared__ __align__(16) float xs[FPB][PPAD];
    __shared__ float partial[FPB][NEURONS * 8];
    const int tid = threadIdx.x;
    const int f0 = blockIdx.x * FPB;

    const float4* src = (const float4*)(xp + (size_t)f0 * PPAD);
    float4* dst = (float4*)(&xs[0][0]);
    #pragma unroll
    for (int i = tid; i < FPB * PPAD4; i += 512) dst[i] = src[i];
    __syncthreads();

    if (tid < NEURONS * 8) {
        const int n = tid >> 3, c = tid & 7;
        const float4* w4 = (const float4*)(wpad + n * PPAD);
        float acc[FPB];
        #pragma unroll
        for (int f = 0; f < FPB; f++) acc[f] = 0.f;
        for (int i = c; i < PPAD4; i += 8) {
            float4 w = w4[i];
            #pragma unroll
            for (int f = 0; f < FPB; f++) {
                float4 a = ((const float4*)xs[f])[i];   // broadcast across n
                acc[f] += a.x * w.x + a.y * w.y + a.z * w.z + a.w * w.w;
            }
        }
        #pragma unroll
        for (int f = 0; f < FPB; f++) partial[f][tid] = acc[f];
    }
    __syncthreads();

    if (tid < FPB * NEURONS) {
        const int f = tid / NEURONS, n = tid - f * NEURONS;
        float s = 0.0f;
        #pragma unroll
        for (int c = 0; c < 8; c++) s += partial[f][n * 8 + c];
        frames[(size_t)(f0 + f) * NEURONS + n] = s + fc_b[n];
    }
}

// ---------------------------------------------------------------------------
// Kernel S: 30-step recurrent scan. One block, 1024 threads.
// wave = batch b, lane = neuron n (lanes 54..63 idle-zero). All frames
// (103.7 KB) prefetched to LDS once; per-step reads hit LDS not L2.
// ---------------------------------------------------------------------------
__global__ __launch_bounds__(1024) void scan_k(
    const float* __restrict__ frames, const float* __restrict__ l_weight,
    const float* __restrict__ h_weight, float* __restrict__ out) {
    __shared__ float fr_s[NFRAMES * NEURONS];   // 25920 floats = 103.7 KB
    __shared__ float wls[16];
    const int tid = threadIdx.x;
    const int b = tid >> 6;     // wave id = batch
    const int n = tid & 63;     // lane = neuron
    const bool active = (n < NEURONS);

    for (int i = tid; i < NFRAMES * NEURONS; i += 1024) fr_s[i] = frames[i];

    float lw[DT], hw_[DT];
    #pragma unroll
    for (int d = 0; d < DT; d++) {
        lw[d]  = active ? l_weight[n * DT + d] : 0.0f;
        hw_[d] = h_weight[d];
    }
    float hist[DT] = {0.f, 0.f, 0.f, 0.f};
    float count = 0.f;
    __syncthreads();

    for (int t = 0; t < STEPS; t++) {
        float my_hsum = 0.f, hterm = 0.f;
        #pragma unroll
        for (int d = 0; d < DT; d++) {
            my_hsum += hist[d] * lw[d];
            hterm   += hist[d] * hw_[d];
        }
        float tot = my_hsum;
        #pragma unroll
        for (int off = 32; off > 0; off >>= 1) tot += __shfl_xor(tot, off, 64);

        float rate = 0.f;
        if (active) {
            float cur = fr_s[(b * STEPS + t) * NEURONS + n] + (tot - my_hsum) + hterm;
            rate = expf(cur);
        }
        float rsum = rate;
        #pragma unroll
        for (int off = 32; off > 0; off >>= 1) rsum += __shfl_xor(rsum, off, 64);
        __syncthreads();
        if (n == 0) wls[b] = rsum;
        __syncthreads();
        float v = (n < 16) ? wls[n] : 0.f;
        #pragma unroll
        for (int off = 32; off > 0; off >>= 1) v += __shfl_xor(v, off, 64);
        float thr = v * (1.0f / (BATCH * NEURONS));

        float s = (active && rate > thr) ? 1.0f : 0.0f;
        count += s;
        hist[0] = hist[1]; hist[1] = hist[2]; hist[2] = hist[3]; hist[3] = s;
    }
    if (active) {
        out[b * NEURONS + n] = count + log1pf(expf(-count));
    }
}

extern "C" void kernel_launch(void* const* d_in, const int* in_sizes, int n_in,
                              void* d_out, int out_size, void* d_ws, size_t ws_size,
                              hipStream_t stream) {
    const float* x        = (const float*)d_in[0];
    const float* fc_w     = (const float*)d_in[1];
    const float* fc_b     = (const float*)d_in[2];
    const float* l_weight = (const float*)d_in[3];
    const float* h_weight = (const float*)d_in[4];
    float* out = (float*)d_out;

    float* wpad   = (float*)d_ws;                       // 54*5632 floats
    float* xp     = wpad + NEURONS * PPAD;              // 480*5632 floats (10.8 MB)
    float* frames = xp + (size_t)NFRAMES * PPAD;        // 480*54 floats

    int wtotal = NEURONS * PPAD;
    repack_w<<<(wtotal + 511) / 512, 512, 0, stream>>>(fc_w, wpad);
    pool_k<<<dim3(PPAD / 256, NFRAMES), 256, 0, stream>>>(x, xp);
    fc_k<<<NFRAMES / FPB, 512, 0, stream>>>(xp, wpad, fc_b, frames);
    scan_k<<<1, 1024, 0, stream>>>(frames, l_weight, h_weight, out);
}

// Round 4
// 939.088 us; speedup vs baseline: 1.0637x; 1.0582x over previous
//
#include <hip/hip_runtime.h>
#include <math.h>

#define NEURONS 54
#define DT 4
#define STEPS 30
#define BATCH 16
#define HW 75
#define P 5625        // 75*75
#define PPAD 5632     // padded to multiple of 4 (16B float4 alignment)
#define PPAD4 (PPAD/4)
#define NFRAMES (BATCH*STEPS)   // 480

// ---------------------------------------------------------------------------
// Kernel W: repack fc_w [54][5625] -> [54][5632], zero-padded rows so each row
// is 16B-aligned for dwordx4 loads in the FC phase.
// ---------------------------------------------------------------------------
__global__ void repack_w(const float* __restrict__ fc_w, float* __restrict__ wpad) {
    int idx = blockIdx.x * blockDim.x + threadIdx.x;
    if (idx >= NEURONS * PPAD) return;
    int n = idx / PPAD, p = idx % PPAD;
    wpad[idx] = (p < P) ? fc_w[n * P + p] : 0.0f;
}

// ---------------------------------------------------------------------------
// Kernel F: fused 8x8 avg-pool + FC (the R1 structure — best measured).
// One block per (b,t) frame; pool 600x600 -> LDS, then 432 threads dot
// against L2-resident fc_w. Summation order bit-identical to R1.
// ---------------------------------------------------------------------------
__global__ __launch_bounds__(512) void pool_fc(
    const float* __restrict__ x, const float* __restrict__ wpad,
    const float* __restrict__ fc_b, float* __restrict__ frames) {
    __shared__ __align__(16) float xp_s[PPAD];
    __shared__ float partial[NEURONS * 8];
    const int bt = blockIdx.x;           // b*30 + t, 0..479
    const int tid = threadIdx.x;
    const float* img = x + (size_t)bt * (600 * 600);

    if (tid < PPAD - P) xp_s[P + tid] = 0.0f;   // zero the pad tail

    // ---- pooling: each thread handles pooled pixels tid, tid+512, ... ----
    for (int p = tid; p < P; p += 512) {
        int ph = p / HW, pw = p - ph * HW;
        const float* base = img + (ph * 8) * 600 + pw * 8;
        float acc = 0.0f;
        #pragma unroll
        for (int r = 0; r < 8; r++) {
            const float4* row = (const float4*)(base + r * 600);
            float4 a = row[0], b4 = row[1];
            acc += (a.x + b4.x) + (a.y + b4.y) + (a.z + b4.z) + (a.w + b4.w);
        }
        xp_s[p] = acc * (1.0f / 64.0f);
    }
    __syncthreads();

    // ---- FC: n = tid/8, chunk c = tid%8, stride 8 float4s ----
    if (tid < NEURONS * 8) {
        int n = tid >> 3, c = tid & 7;
        const float4* w4 = (const float4*)(wpad + n * PPAD);
        const float4* x4 = (const float4*)xp_s;
        float acc = 0.0f;
        for (int i = c; i < PPAD4; i += 8) {
            float4 a = x4[i], w = w4[i];
            acc += a.x * w.x + a.y * w.y + a.z * w.z + a.w * w.w;
        }
        partial[tid] = acc;
    }
    __syncthreads();
    if (tid < NEURONS) {
        float s = 0.0f;
        #pragma unroll
        for (int c = 0; c < 8; c++) s += partial[tid * 8 + c];
        frames[bt * NEURONS + tid] = s + fc_b[tid];
    }
}

// ---------------------------------------------------------------------------
// Kernel S: 30-step recurrent scan. One block, 1024 threads.
// wave = batch b, lane = neuron n (lanes 54..63 idle-zero). All frames
// (103.7 KB) prefetched to LDS once; per-step reads hit LDS not L2.
// ---------------------------------------------------------------------------
__global__ __launch_bounds__(1024) void scan_k(
    const float* __restrict__ frames, const float* __restrict__ l_weight,
    const float* __restrict__ h_weight, float* __restrict__ out) {
    __shared__ float fr_s[NFRAMES * NEURONS];   // 25920 floats = 103.7 KB
    __shared__ float wls[16];
    const int tid = threadIdx.x;
    const int b = tid >> 6;     // wave id = batch
    const int n = tid & 63;     // lane = neuron
    const bool active = (n < NEURONS);

    for (int i = tid; i < NFRAMES * NEURONS; i += 1024) fr_s[i] = frames[i];

    float lw[DT], hw_[DT];
    #pragma unroll
    for (int d = 0; d < DT; d++) {
        lw[d]  = active ? l_weight[n * DT + d] : 0.0f;
        hw_[d] = h_weight[d];
    }
    float hist[DT] = {0.f, 0.f, 0.f, 0.f};
    float count = 0.f;
    __syncthreads();

    for (int t = 0; t < STEPS; t++) {
        float my_hsum = 0.f, hterm = 0.f;
        #pragma unroll
        for (int d = 0; d < DT; d++) {
            my_hsum += hist[d] * lw[d];
            hterm   += hist[d] * hw_[d];
        }
        float tot = my_hsum;
        #pragma unroll
        for (int off = 32; off > 0; off >>= 1) tot += __shfl_xor(tot, off, 64);

        float rate = 0.f;
        if (active) {
            float cur = fr_s[(b * STEPS + t) * NEURONS + n] + (tot - my_hsum) + hterm;
            rate = expf(cur);
        }
        float rsum = rate;
        #pragma unroll
        for (int off = 32; off > 0; off >>= 1) rsum += __shfl_xor(rsum, off, 64);
        __syncthreads();
        if (n == 0) wls[b] = rsum;
        __syncthreads();
        float v = (n < 16) ? wls[n] : 0.f;
        #pragma unroll
        for (int off = 32; off > 0; off >>= 1) v += __shfl_xor(v, off, 64);
        float thr = v * (1.0f / (BATCH * NEURONS));

        float s = (active && rate > thr) ? 1.0f : 0.0f;
        count += s;
        hist[0] = hist[1]; hist[1] = hist[2]; hist[2] = hist[3]; hist[3] = s;
    }
    if (active) {
        out[b * NEURONS + n] = count + log1pf(expf(-count));
    }
}

extern "C" void kernel_launch(void* const* d_in, const int* in_sizes, int n_in,
                              void* d_out, int out_size, void* d_ws, size_t ws_size,
                              hipStream_t stream) {
    const float* x        = (const float*)d_in[0];
    const float* fc_w     = (const float*)d_in[1];
    const float* fc_b     = (const float*)d_in[2];
    const float* l_weight = (const float*)d_in[3];
    const float* h_weight = (const float*)d_in[4];
    float* out = (float*)d_out;

    float* wpad   = (float*)d_ws;                 // 54*5632 floats = 1.22 MB
    float* frames = wpad + NEURONS * PPAD;        // 480*54 floats  = 104 KB

    int wtotal = NEURONS * PPAD;
    repack_w<<<(wtotal + 511) / 512, 512, 0, stream>>>(fc_w, wpad);
    pool_fc<<<NFRAMES, 512, 0, stream>>>(x, wpad, fc_b, frames);
    scan_k<<<1, 1024, 0, stream>>>(frames, l_weight, h_weight, out);
}